// Round 10
// baseline (53.430 us; speedup 1.0000x reference)
//
#include <hip/hip_runtime.h>
#include <stdint.h>

#define UNITS  512
#define IN_DIM 1024
#define KCONN  32
#define BATCH  16384

#define BM 64
#define BN 256
#define BK 64
#define NT 256            // 4 waves

typedef _Float16 f16x8 __attribute__((ext_vector_type(8)));
typedef __fp16   hf16x2 __attribute__((ext_vector_type(2)));
typedef float    f32x4 __attribute__((ext_vector_type(4)));

// ---------------- Kernel 1: top-32 per unit -> dense f16 W' row ----------------
// pert[u,i] = D[u,i] + GN[0,u,i]; select the 32 largest (index SET is all that
// matters; r4-r8-verified DPP selection). Output: Bt[u][0..1023] f16 with
// (f16)W[u,i] at selected i, 0 elsewhere. Zeros make the GEMM's extra terms
// contribute exactly 0, so the sum is the same 32-term f32 sum as the sparse
// kernel.

template <int CTRL, int RM>
__device__ __forceinline__ float dppmax(float m) {
    int t = __builtin_amdgcn_update_dpp(0xFF800000, __float_as_int(m),
                                        CTRL, RM, 0xf, false);
    return fmaxf(m, __int_as_float(t));
}

__global__ __launch_bounds__(64) void topk_dense(const float* __restrict__ D,
                                                 const float* __restrict__ GN,
                                                 const float* __restrict__ W,
                                                 _Float16* __restrict__ Bt) {
    const int u = blockIdx.x;
    const int l = threadIdx.x;

    float cand[16];
#pragma unroll
    for (int j = 0; j < 16; ++j) {
        int i = l + 64 * j;                          // coalesced
        cand[j] = D[u * IN_DIM + i] + GN[u * IN_DIM + i];
    }

    int mykeep = -1;

    for (int t = 0; t < KCONN; ++t) {
        float bv = cand[0];
        int bs = 0;
#pragma unroll
        for (int j = 1; j < 16; ++j) {
            bool gt = cand[j] > bv;
            bv = gt ? cand[j] : bv;
            bs = gt ? j : bs;
        }
        float m = bv;
        m = dppmax<0x111, 0xf>(m);
        m = dppmax<0x112, 0xf>(m);
        m = dppmax<0x114, 0xf>(m);
        m = dppmax<0x118, 0xf>(m);
        m = dppmax<0x142, 0xa>(m);   // row_bcast15 -> rows 1,3
        m = dppmax<0x143, 0xc>(m);   // row_bcast31 -> rows 2,3
        float gmax = __int_as_float(__builtin_amdgcn_readlane(__float_as_int(m), 63));

        unsigned long long mask = __ballot(bv == gmax);
        int owner = __ffsll((long long)mask) - 1;
        int slot = __builtin_amdgcn_readlane(bs, owner);
        int idx = slot * 64 + owner;

        if (l == t) mykeep = idx;
        bool own = (l == owner);
#pragma unroll
        for (int j = 0; j < 16; ++j)
            cand[j] = (own && j == slot) ? -__builtin_huge_valf() : cand[j];
    }

    // build dense row in LDS, then stream out coalesced
    __shared__ uint32_t rowbuf[IN_DIM / 2];          // 1024 f16 = 2 KB
#pragma unroll
    for (int j = 0; j < 8; ++j) rowbuf[l + 64 * j] = 0;
    __syncthreads();
    if (l < KCONN) {
        union { _Float16 h; uint16_t b; } cv;
        cv.h = (_Float16)W[u * IN_DIM + mykeep];
        ((uint16_t*)rowbuf)[mykeep] = cv.b;
    }
    __syncthreads();
    uint4* out = (uint4*)(Bt + (size_t)u * IN_DIM);
    const uint4* rb = (const uint4*)rowbuf;
    out[l]      = rb[l];
    out[l + 64] = rb[l + 64];
}

// ---------------- Kernel 2: dense f16 MFMA GEMM ----------------
// y[M=16384][N=512] = x(f32->f16)[M][K=1024] @ Bt[N][K]^T + bias
// BM=64, BN=256, BK=64, 256 thr (4 waves), grid 512 (bid>>1 = m-tile,
// bid&1 = n-half so the 2 n-tiles sharing x run ~concurrently -> L3 reuse).
// LDS 40 KB (As 8K + Bs 32K) -> 4 blocks/CU.  Both tiles stored with the T2
// row-XOR chunk swizzle phys = row*128 + (kb ^ ((row&7)<<4)) so fragment
// ds_read_b128 (16 lanes @ 128B stride) is conflict-free.
// A: reg-staged f32->f16 via v_cvt_pkrtz. B: global_load_lds width 16 with
// pre-swizzled GLOBAL source (linear LDS dest; rule #21).
// MFMA 16x16x32 f16; layouts: A/B lane: row=lane&15, k=8*(lane>>4)+j;
// C/D: col(n)=lane&15, row(m)=(lane>>4)*4+reg  [m89/m91-verified].

typedef const uint32_t __attribute__((address_space(1)))* gp1_t;
typedef uint32_t __attribute__((address_space(3)))* lp3_t;

__device__ __forceinline__ void gload16(const void* g, void* l) {
    __builtin_amdgcn_global_load_lds((gp1_t)g, (lp3_t)l, 16, 0, 0);
}

__device__ __forceinline__ uint32_t pkrtz(float a, float b) {
    union { hf16x2 h; uint32_t u; } cv;
    cv.h = __builtin_amdgcn_cvt_pkrtz(a, b);
    return cv.u;
}

__global__ __launch_bounds__(NT, 4) void gemm_kernel(const float* __restrict__ x,
                                                     const float* __restrict__ bias,
                                                     const _Float16* __restrict__ Bt,
                                                     float* __restrict__ y) {
    __shared__ char As[BM * 128];                   // 8 KB  (64 rows x 64 f16)
    __shared__ char Bs[BN * 128];                   // 32 KB (256 rows x 64 f16)

    const int tid = threadIdx.x;
    const int w = tid >> 6;                         // wave 0..3
    const int l = tid & 63;
    const int mb = ((int)blockIdx.x >> 1) * BM;
    const int nb = ((int)blockIdx.x & 1) * BN;

    // A staging: thread t -> row t>>2 (0..63), k-quarter t&3 (16 f32)
    const int arow = tid >> 2;
    const int akq = tid & 3;
    const float* xp = x + (size_t)(mb + arow) * IN_DIM + akq * 16;
    char* asw = As + arow * 128;
    const uint32_t akb0 = (uint32_t)(akq * 32) ^ (uint32_t)((arow & 7) << 4);
    const uint32_t akb1 = (uint32_t)(akq * 32 + 16) ^ (uint32_t)((arow & 7) << 4);

    // B staging (global_load_lds): call c of wave w covers Bs rows
    // seg*8..seg*8+7 (seg = w*8+c); lane -> row seg*8 + (l>>3), chunk (l&7).
    // Global src pre-swizzled so linear LDS + swizzled read = involution.
    const int brlane = l >> 3;                      // 0..7
    const uint32_t bswz = ((uint32_t)(l & 7) << 4) ^ ((uint32_t)brlane << 4);
    const char* btb = (const char*)Bt + (size_t)nb * (IN_DIM * 2) +
                      (size_t)brlane * (IN_DIM * 2) + bswz;

    f32x4 acc[4][4] = {};

    for (int ks = 0; ks < IN_DIM / BK; ++ks) {
        // issue A global loads (regs) before the barrier
        float4 v0 = ((const float4*)xp)[0];
        float4 v1 = ((const float4*)xp)[1];
        float4 v2 = ((const float4*)xp)[2];
        float4 v3 = ((const float4*)xp)[3];
        xp += BK;

        __syncthreads();                            // prev compute done

        *(uint4*)(asw + akb0) = make_uint4(pkrtz(v0.x, v0.y), pkrtz(v0.z, v0.w),
                                           pkrtz(v1.x, v1.y), pkrtz(v1.z, v1.w));
        *(uint4*)(asw + akb1) = make_uint4(pkrtz(v2.x, v2.y), pkrtz(v2.z, v2.w),
                                           pkrtz(v3.x, v3.y), pkrtz(v3.z, v3.w));

        const size_t kso = (size_t)ks * 128;
#pragma unroll
        for (int c = 0; c < 8; ++c) {
            const int seg = w * 8 + c;
            gload16(btb + (size_t)seg * 8 * (IN_DIM * 2) + kso, Bs + seg * 1024);
        }

        __syncthreads();                            // staging visible (vmcnt+lgkm drain)

#pragma unroll
        for (int kh = 0; kh < 2; ++kh) {
            const uint32_t kb = (uint32_t)(kh * 64 + ((l >> 4) << 4));
            f16x8 af[4], bf[4];
#pragma unroll
            for (int mf = 0; mf < 4; ++mf) {
                const int row = mf * 16 + (l & 15);
                af[mf] = *(const f16x8*)(As + row * 128 + (kb ^ ((row & 7) << 4)));
            }
#pragma unroll
            for (int nf = 0; nf < 4; ++nf) {
                const int row = w * 64 + nf * 16 + (l & 15);
                bf[nf] = *(const f16x8*)(Bs + row * 128 + (kb ^ ((row & 7) << 4)));
            }
#pragma unroll
            for (int mf = 0; mf < 4; ++mf)
#pragma unroll
                for (int nf = 0; nf < 4; ++nf)
                    acc[mf][nf] = __builtin_amdgcn_mfma_f32_16x16x32_f16(
                        af[mf], bf[nf], acc[mf][nf], 0, 0, 0);
        }
    }

    // epilogue: y = acc + bias
#pragma unroll
    for (int nf = 0; nf < 4; ++nf) {
        const int n = nb + w * 64 + nf * 16 + (l & 15);
        const float bv = bias[n];
#pragma unroll
        for (int mf = 0; mf < 4; ++mf) {
            const int m0 = mb + mf * 16 + ((l >> 4) << 2);
#pragma unroll
            for (int r = 0; r < 4; ++r)
                y[(size_t)(m0 + r) * UNITS + n] = acc[mf][nf][r] + bv;
        }
    }
}

extern "C" void kernel_launch(void* const* d_in, const int* in_sizes, int n_in,
                              void* d_out, int out_size, void* d_ws, size_t ws_size,
                              hipStream_t stream) {
    const float* x  = (const float*)d_in[0];   // [16384,1024]
    const float* W  = (const float*)d_in[1];   // [512,1024]
    const float* bv = (const float*)d_in[2];   // [512]
    const float* D  = (const float*)d_in[3];   // [512,1024]
    const float* GN = (const float*)d_in[4];   // [1,512,1024]
    float* y = (float*)d_out;                  // [16384,512]

    _Float16* Bt = (_Float16*)d_ws;            // 512*1024*2B = 1 MB scratch

    topk_dense<<<UNITS, 64, 0, stream>>>(D, GN, W, Bt);
    gemm_kernel<<<(BATCH / BM) * (UNITS / BN), NT, 0, stream>>>(x, bv, Bt, y);
}